// Round 13
// baseline (212.017 us; speedup 1.0000x reference)
//
#include <hip/hip_runtime.h>

#define PSZ 16
#define BATCH 32
#define IMGH 512
#define IMGW 512
#define CH 3
#define NPATCH 1024            // patches per image (32x32)
#define K_TOT 768
#define N_TOT 256
#define ROWSTRIDE (IMGW*CH)    // 1536 floats per image row
#define IMGSTRIDE (IMGH*IMGW*CH)

#define BM 64
#define BN 128
#define BK 64
#define NKIT 12

typedef __bf16 bf16_t;
typedef bf16_t bf16x8 __attribute__((ext_vector_type(8)));
typedef float f32x4 __attribute__((ext_vector_type(4)));

// ---------------- prep: W[768][256] fp32 -> fragment-direct hi/lo bf16x8 arrays ----------
// frag index t = ((bcg*12 + kit)*2 + ks)*64 + lane, value[e] =
//   W[(kit*64 + ks*32 + (lane>>4)*8 + e)*256 + bcg*16 + (lane&15)]
__global__ void prep_w(const float* __restrict__ Wsrc,
                       bf16x8* __restrict__ wfh, bf16x8* __restrict__ wfl) {
    int t = blockIdx.x * 256 + threadIdx.x;      // 0..24575
    int lane = t & 63;
    int ks = (t >> 6) & 1;
    int rest = t >> 7;                           // 0..191
    int kit = rest % 12;
    int bcg = rest / 12;                         // 0..15
    int col = bcg * 16 + (lane & 15);
    int kbase = kit * 64 + ks * 32 + ((lane >> 4) << 3);
    bf16x8 h, l;
#pragma unroll
    for (int e = 0; e < 8; ++e) {
        float v = Wsrc[(size_t)(kbase + e) * N_TOT + col];
        bf16_t hh = (bf16_t)v;
        h[e] = hh;
        l[e] = (bf16_t)(v - (float)hh);
    }
    wfh[t] = h;
    wfl[t] = l;
}

// ---------------- cls row: out[b,0,:] = cls + pos ----------------
__global__ void cls_add(const float* __restrict__ cls, const float* __restrict__ pos,
                        float* __restrict__ out) {
    int i = blockIdx.x * 256 + threadIdx.x;   // 8192
    int b = i >> 8, h = i & 255;
    size_t o = (size_t)b * (NPATCH + 1) * N_TOT + h;
    out[o] = cls[i] + pos[o];
}

__device__ __forceinline__ void gload_lds16(const void* g, void* l) {
    __builtin_amdgcn_global_load_lds(
        (const __attribute__((address_space(1))) void*)g,
        (__attribute__((address_space(3))) void*)l, 16, 0, 0);
}

// ---------------- main: A via global_load_lds (fp32 + XOR swizzle), B reg-prefetch ----------
__global__ __launch_bounds__(256, 2)
void patch_gemm(const float* __restrict__ x,
                const bf16x8* __restrict__ wfh, const bf16x8* __restrict__ wfl,
                const float* __restrict__ bias, const float* __restrict__ pos,
                float* __restrict__ out) {
    // A tile fp32, 64 rows x 64 floats (256B/row), 16B chunks XOR-swizzled:
    // slot c holds content chunk c' = (c&8)|((c&7)^(row&7))  (involution)
    __shared__ float Af[2][BM * BK];

    const int bid = blockIdx.x;
    const int t = (bid & 7) * 128 + (bid >> 3);   // bijective XCD swizzle (1024=8*128)
    const int mtile = t >> 1;
    const int ntile = t & 1;

    const int tid = threadIdx.x;
    const int lane = tid & 63;
    const int wid = tid >> 6;
    const int wr = wid >> 1, wc = wid & 1;        // 2x2 wave grid; wave tile 32x64

    const int m0 = mtile * BM;
    const int n0 = ntile * BN;

    f32x4 acc[2][4] = {};

    const int l15 = lane & 15;
    const int lg = lane >> 4;                     // 0..3
    const int bcg0 = ntile * 8 + wc * 4;

    // ---- staging geometry: 4 rounds/tile; round r covers rows wid*16+r*4 .. +3
    // thread row R = wid*16 + r*4 + (lane>>4), chunk slot = lane&15 (linear dest),
    // global source pre-swizzled: content chunk c' = (c&8)|((c&7)^(R&7))
    const float* gsrc[4];
    int kf[4];
#pragma unroll
    for (int r = 0; r < 4; ++r) {
        int R = wid * 16 + r * 4 + lg;
        int c = l15;
        int cp = (c & 8) | ((c & 7) ^ (R & 7));
        kf[r] = cp << 2;                          // kfloat within the 64-float k-tile
        int pm = m0 + R;
        int b = pm >> 10, pid = pm & 1023;
        int gr = pid >> 5, gc = pid & 31;
        gsrc[r] = x + (size_t)b * IMGSTRIDE + (gr * PSZ) * ROWSTRIDE + gc * (PSZ * CH);
    }

    // read offsets (bytes) for A fragments: rdoff[ks][ar], second granule = ^16
    int rdoff[2][2];
#pragma unroll
    for (int ks = 0; ks < 2; ++ks)
#pragma unroll
        for (int ar = 0; ar < 2; ++ar) {
            int R = wr * 32 + ar * 16 + l15;
            int c0 = ks * 8 + ((lg * 2) ^ (l15 & 7));
            rdoff[ks][ar] = R * 256 + c0 * 16;
        }

#define STAGE(KIT, BUF)                                                        \
    {                                                                          \
        _Pragma("unroll")                                                      \
        for (int r = 0; r < 4; ++r) {                                          \
            int d = (KIT) * BK + kf[r];                                        \
            int prow = d / 48, poff = d - prow * 48;                           \
            gload_lds16(gsrc[r] + prow * ROWSTRIDE + poff,                     \
                        &Af[BUF][(wid * 16 + r * 4) * BK]);                    \
        }                                                                      \
    }

#define LOADB(KIT, BH, BL)                                                     \
    {                                                                          \
        _Pragma("unroll")                                                      \
        for (int ks = 0; ks < 2; ++ks)                                         \
            _Pragma("unroll")                                                  \
            for (int bc = 0; bc < 4; ++bc) {                                   \
                int idx = (((bcg0 + bc) * 12 + (KIT)) * 2 + ks) * 64 + lane;   \
                BH[ks][bc] = wfh[idx];                                         \
                BL[ks][bc] = wfl[idx];                                         \
            }                                                                  \
    }

#define COMPUTE(BUF, BH, BL)                                                   \
    {                                                                          \
        _Pragma("unroll")                                                      \
        for (int ks = 0; ks < 2; ++ks)                                         \
            _Pragma("unroll")                                                  \
            for (int ar = 0; ar < 2; ++ar) {                                   \
                const char* base = (const char*)&Af[BUF][0];                   \
                f32x4 f0 = *(const f32x4*)(base + rdoff[ks][ar]);              \
                f32x4 f1 = *(const f32x4*)(base + (rdoff[ks][ar] ^ 16));       \
                bf16x8 ah, al;                                                 \
                ah[0]=(bf16_t)f0[0]; al[0]=(bf16_t)(f0[0]-(float)ah[0]);       \
                ah[1]=(bf16_t)f0[1]; al[1]=(bf16_t)(f0[1]-(float)ah[1]);       \
                ah[2]=(bf16_t)f0[2]; al[2]=(bf16_t)(f0[2]-(float)ah[2]);       \
                ah[3]=(bf16_t)f0[3]; al[3]=(bf16_t)(f0[3]-(float)ah[3]);       \
                ah[4]=(bf16_t)f1[0]; al[4]=(bf16_t)(f1[0]-(float)ah[4]);       \
                ah[5]=(bf16_t)f1[1]; al[5]=(bf16_t)(f1[1]-(float)ah[5]);       \
                ah[6]=(bf16_t)f1[2]; al[6]=(bf16_t)(f1[2]-(float)ah[6]);       \
                ah[7]=(bf16_t)f1[3]; al[7]=(bf16_t)(f1[3]-(float)ah[7]);       \
                _Pragma("unroll")                                              \
                for (int bc = 0; bc < 4; ++bc) {                               \
                    acc[ar][bc] = __builtin_amdgcn_mfma_f32_16x16x32_bf16(ah, BH[ks][bc], acc[ar][bc], 0, 0, 0); \
                    acc[ar][bc] = __builtin_amdgcn_mfma_f32_16x16x32_bf16(ah, BL[ks][bc], acc[ar][bc], 0, 0, 0); \
                    acc[ar][bc] = __builtin_amdgcn_mfma_f32_16x16x32_bf16(al, BH[ks][bc], acc[ar][bc], 0, 0, 0); \
                }                                                              \
            }                                                                  \
    }

    // B register sets: ping-pong, all indices compile-time (rule #20)
    bf16x8 B0h[2][4], B0l[2][4], B1h[2][4], B1l[2][4];

    // ---- prologue ----
    STAGE(0, 0);
    LOADB(0, B0h, B0l);
    __syncthreads();

    for (int kp = 0; kp < 6; ++kp) {
        {   // kit = 2kp: consume buf0/set0, prefetch kit+1 -> buf1/set1
            const int kit = 2 * kp;
            STAGE(kit + 1, 1);
            LOADB(kit + 1, B1h, B1l);
            COMPUTE(0, B0h, B0l);
            __syncthreads();
        }
        {   // kit = 2kp+1: consume buf1/set1, prefetch kit+2 -> buf0/set0
            const int kit = 2 * kp + 1;
            if (kp < 5) {
                STAGE(kit + 1, 0);
                LOADB(kit + 1, B0h, B0l);
            }
            COMPUTE(1, B1h, B1l);
            __syncthreads();
        }
    }

    // ---- epilogue: C/D layout col=lane&15, row=(lane>>4)*4+j ----
    const int colbase = n0 + wc * 64;
    float bvals[4];
#pragma unroll
    for (int bc = 0; bc < 4; ++bc) bvals[bc] = bias[colbase + bc * 16 + l15];

#pragma unroll
    for (int ar = 0; ar < 2; ++ar) {
        int rbase = m0 + wr * 32 + ar * 16 + (lg << 2);
#pragma unroll
        for (int j = 0; j < 4; ++j) {
            int pm = rbase + j;
            int b = pm >> 10, p = pm & 1023;
            size_t orow = (size_t)(b * (NPATCH + 1) + 1 + p) * N_TOT;
#pragma unroll
            for (int bc = 0; bc < 4; ++bc) {
                int col = colbase + bc * 16 + l15;
                out[orow + col] = acc[ar][bc][j] + bvals[bc] + pos[orow + col];
            }
        }
    }
#undef STAGE
#undef LOADB
#undef COMPUTE
}

extern "C" void kernel_launch(void* const* d_in, const int* in_sizes, int n_in,
                              void* d_out, int out_size, void* d_ws, size_t ws_size,
                              hipStream_t stream) {
    const float* x    = (const float*)d_in[0];
    const float* W    = (const float*)d_in[1];
    const float* bias = (const float*)d_in[2];
    const float* cls  = (const float*)d_in[3];
    const float* pos  = (const float*)d_in[4];
    float* out = (float*)d_out;

    bf16x8* wfh = (bf16x8*)d_ws;
    bf16x8* wfl = wfh + 24576;

    prep_w<<<96, 256, 0, stream>>>(W, wfh, wfl);
    cls_add<<<32, 256, 0, stream>>>(cls, pos, out);
    patch_gemm<<<1024, 256, 0, stream>>>(x, wfh, wfl, bias, pos, out);
}